// Round 7
// baseline (19046.156 us; speedup 1.0000x reference)
//
#include <hip/hip_runtime.h>

typedef __bf16 bf16;
typedef __bf16 bf16x8 __attribute__((ext_vector_type(8)));
typedef float  f32x16 __attribute__((ext_vector_type(16)));
typedef unsigned short u16;

#define MFMA(a,b,c) __builtin_amdgcn_mfma_f32_32x32x16_bf16((a),(b),(c),0,0,0)

#define BSZ  2048
#define H    256
#define NOUT 5
#define BM   32              // batch rows per block
#define NBLK (BSZ/BM)        // 64 blocks, zero inter-block communication

// packed weight fragments (16B each): big mats frag id = (tile*16+ks)*64+lane
// (VERIFIED layout, rounds 1-6)
#define F_WHH1 0
#define F_WIH2 24576
#define F_WHH2 49152
#define F_WIH1 73728
#define F_LIN  75264
#define F_TOTAL 76288

__device__ bf16x8 g_pk[F_TOTAL];

__global__ void prepack_kernel(const float* __restrict__ wih1,
                               const float* __restrict__ whh1,
                               const float* __restrict__ wih2,
                               const float* __restrict__ whh2,
                               const float* __restrict__ lin_w) {
  int fid = blockIdx.x * 256 + threadIdx.x;
  if (fid >= F_TOTAL) return;
  bf16x8 v;
  if (fid < F_WIH1) {
    const float* W = (fid < F_WIH2) ? whh1 : (fid < F_WHH2) ? wih2 : whh2;
    int r    = fid % 24576;
    int tile = r >> 10;
    int ks   = (r >> 6) & 15;
    int lane = r & 63;
    int n = tile * 32 + (lane & 31);
    int k = ks * 16 + (lane >> 5) * 8;
    const float* p = W + n * 256 + k;
#pragma unroll
    for (int i = 0; i < 8; ++i) v[i] = (bf16)p[i];
  } else if (fid < F_LIN) {
    int r    = fid - F_WIH1;
    int tile = r >> 6;
    int lane = r & 63;
    int n  = tile * 32 + (lane & 31);
    int k0 = (lane >> 5) * 8;
#pragma unroll
    for (int i = 0; i < 8; ++i) {
      int kk = k0 + i;
      v[i] = (kk < 8) ? (bf16)wih1[n * 8 + kk] : (bf16)0.f;
    }
  } else {
    int r    = fid - F_LIN;
    int ks   = r >> 6;
    int lane = r & 63;
    int n = lane & 31;
    int k = ks * 16 + (lane >> 5) * 8;
#pragma unroll
    for (int i = 0; i < 8; ++i)
      v[i] = (n < NOUT) ? (bf16)lin_w[n * 256 + k + i] : (bf16)0.f;
  }
  g_pk[fid] = v;
}

__device__ __forceinline__ float sigmoidf_(float x) { return 1.f / (1.f + __expf(-x)); }
__device__ __forceinline__ float tanhf_(float x) {
  float e = __expf(-2.f * x);
  return (1.f - e) / (1.f + e);
}
__device__ __forceinline__ f32x16 z16() {
  f32x16 z;
#pragma unroll
  for (int i = 0; i < 16; ++i) z[i] = 0.f;
  return z;
}
__device__ __forceinline__ u16 bfb(float x) { bf16 b = (bf16)x; return *(u16*)&b; }

// swizzled bf16 A-tile element (row, unit u of 8 cols): conflict-free ds_read_b128
__device__ __forceinline__ bf16x8 ldA(const u16* buf, int row, int u) {
  return *(const bf16x8*)&buf[(row << 8) + ((u ^ (row & 31)) << 3)];
}
__device__ __forceinline__ bf16x8 ldX(const u16* xsb, int row, int hv) {
  return *(const bf16x8*)&xsb[(row << 4) + (hv << 3)];
}

// Zero-sync batch-split GRU. Block b owns batch rows [32b,32b+32) for all T
// steps; every block streams the full weight set from its XCD's L2 each step
// (weights fit L2: 1.18MB). 8 waves; wave w owns h-dims [32w,32w+32) of both
// layers: gate tiles {w, w+8, w+16}. Structure = round-1 verified kernel +
// (a) 12 reg-resident + 11 LDS-resident frags/wave, (b) explicit 8-deep
// va/vb staging for streamed frags, (c) head/u prefetch. 3 barriers/step,
// no inter-block sync of any kind.
__global__ __launch_bounds__(512, 2) void gru_kernel(
    const int* __restrict__ plen_p,
    const float* __restrict__ rnn_in,
    const float* __restrict__ out0,
    const float* __restrict__ h01,
    const float* __restrict__ h02,
    const float* __restrict__ bih1, const float* __restrict__ bhh1,
    const float* __restrict__ bih2, const float* __restrict__ bhh2,
    const float* __restrict__ lin_b,
    float* __restrict__ out) {
  __shared__ u16 h1s[2][BM * 256];     // 16KB each, swizzled, double-buffered
  __shared__ u16 h2s[2][BM * 256];
  __shared__ u16 xs[BM * 16];          // [out(5), u(3), zeros(8)]
  __shared__ u16 ldsW[88 * 512];       // 88 LDS-resident frags (11/wave), 88KB

  const int T   = plen_p[0];
  const int tid = threadIdx.x;
  const int w   = tid >> 6;
  const int l   = tid & 63;
  const int col = l & 31;
  const int hv  = l >> 5;
  const int b0  = blockIdx.x * BM;
  const int jd  = w * 32 + col;        // this lane's h-dim / gate column

  // ---- per-lane biases ----
  float br1 = bih1[jd] + bhh1[jd];
  float bz1 = bih1[H + jd] + bhh1[H + jd];
  float bi1 = bih1[2 * H + jd];
  float bh1 = bhh1[2 * H + jd];
  float br2 = bih2[jd] + bhh2[jd];
  float bz2 = bih2[H + jd] + bhh2[H + jd];
  float bi2 = bih2[2 * H + jd];
  float bh2 = bhh2[2 * H + jd];
  float lb  = (w == 2 && col < NOUT) ? lin_b[col] : 0.f;

  // ---- register-resident frags: wih1 r/z/n + whh1_r ks0..8 ----
  bf16x8 wf[12];
  wf[0] = g_pk[F_WIH1 + w * 64 + l];
  wf[1] = g_pk[F_WIH1 + (w + 8) * 64 + l];
  wf[2] = g_pk[F_WIH1 + (w + 16) * 64 + l];
#pragma unroll
  for (int ks = 0; ks < 9; ++ks) wf[3 + ks] = g_pk[F_WHH1 + (w * 16 + ks) * 64 + l];

  // ---- LDS-resident frags: slots w*11+j: j<7 -> whh1_r ks9..15; else whh1_z ks0..3
#pragma unroll
  for (int j = 0; j < 11; ++j) {
    int src = (j < 7) ? (F_WHH1 + (w * 16 + 9 + j) * 64)
                      : (F_WHH1 + ((w + 8) * 16 + (j - 7)) * 64);
    bf16x8 f = g_pk[src + l];
    *(bf16x8*)&ldsW[(w * 11 + j) * 512 + l * 8] = f;
  }
#define LDSW(s) (*(const bf16x8*)&ldsW[(s) * 512 + l * 8])

  // ---- fp32 master h state in C/D layout: reg q -> row (q&3)+8*(q>>2)+4*hv
  float h1r[16], h2r[16];
#pragma unroll
  for (int q = 0; q < 16; ++q) {
    int m  = (q & 3) + 8 * (q >> 2) + 4 * hv;
    h1r[q] = h01[(size_t)(b0 + m) * H + jd];
    h2r[q] = h02[(size_t)(b0 + m) * H + jd];
  }

  // ---- LDS h init (bf16, swizzled) ----
  for (int r = tid; r < BM * 32; r += 512) {
    int m = r >> 5, u8 = r & 31;
    const float* p1 = h01 + (size_t)(b0 + m) * H + u8 * 8;
    const float* p2 = h02 + (size_t)(b0 + m) * H + u8 * 8;
    bf16x8 v1, v2;
#pragma unroll
    for (int i = 0; i < 8; ++i) { v1[i] = (bf16)p1[i]; v2[i] = (bf16)p2[i]; }
    int off = (m << 8) + ((u8 ^ m) << 3);
    *(bf16x8*)&h1s[0][off] = v1;
    *(bf16x8*)&h2s[0][off] = v2;
  }
  // ---- xs init ----
  if (tid < 256) { int m = tid >> 3, c = 8 + (tid & 7); xs[m * 16 + c] = 0; }
  if (tid < 160) { int m = tid / 5, c = tid % 5; xs[m * 16 + c] = bfb(out0[(size_t)(b0 + m) * NOUT + c]); }
  if (tid >= 256 && tid < 352) {
    int r2 = tid - 256; int m = r2 / 3, c = r2 % 3;
    xs[m * 16 + 5 + c] = bfb(rnn_in[(size_t)(b0 + m) * 4 + c]);
  }
  __syncthreads();

  for (int t = 0; t < T; ++t) {
    const int par = t & 1;
    const u16* h1c = h1s[par];  u16* h1n = h1s[par ^ 1];
    const u16* h2c = h2s[par];  u16* h2n = h2s[par ^ 1];

    // u(t+1) prefetch (wave 3; both lane-halves load the same row: benign)
    float ux = 0.f, uy = 0.f, uz = 0.f;
    if (w == 3 && t + 1 < T) {
      const float4 uu = *(const float4*)&rnn_in[((size_t)(t + 1) * BSZ + b0 + col) * 4];
      ux = uu.x; uy = uu.y; uz = uu.z;
    }

    // ======== phase A: layer 1 (whh1·h1 + wih1·x) ========
    bf16x8 va[8], vb[8];
    const bf16x8* bz = g_pk + F_WHH1 + (w + 8) * 1024 + l;    // whh1_z
    const bf16x8* bn = g_pk + F_WHH1 + (w + 16) * 1024 + l;   // whh1_n
#pragma unroll
    for (int k = 0; k < 8; ++k) va[k] = bz[(4 + k) * 64];     // z ks4..11
#pragma unroll
    for (int k = 0; k < 4; ++k) vb[k] = bz[(12 + k) * 64];    // z ks12..15
#pragma unroll
    for (int k = 0; k < 4; ++k) vb[4 + k] = bn[k * 64];       // n ks0..3

    f32x16 accR, accZ, accNi, accNh;
    {
      f32x16 zz = z16();
      bf16x8 ax = ldX(xs, col, hv);
      accR  = MFMA(ax, wf[0], zz);
      accZ  = MFMA(ax, wf[1], zz);
      accNi = MFMA(ax, wf[2], zz);
      accNh = zz;
    }
#pragma unroll
    for (int ks = 0; ks < 9; ++ks) accR = MFMA(ldA(h1c, col, 2 * ks + hv), wf[3 + ks], accR);
#pragma unroll
    for (int j = 0; j < 7; ++j)    accR = MFMA(ldA(h1c, col, 2 * (9 + j) + hv), LDSW(w * 11 + j), accR);
#pragma unroll
    for (int ks = 0; ks < 4; ++ks) accZ = MFMA(ldA(h1c, col, 2 * ks + hv), LDSW(w * 11 + 7 + ks), accZ);
#pragma unroll
    for (int k = 0; k < 8; ++k) accZ = MFMA(ldA(h1c, col, 2 * (4 + k) + hv), va[k], accZ);
#pragma unroll
    for (int k = 0; k < 8; ++k) va[k] = bn[(4 + k) * 64];     // n ks4..11
#pragma unroll
    for (int k = 0; k < 4; ++k) accZ = MFMA(ldA(h1c, col, 2 * (12 + k) + hv), vb[k], accZ);
#pragma unroll
    for (int k = 0; k < 4; ++k) accNh = MFMA(ldA(h1c, col, 2 * k + hv), vb[4 + k], accNh);
#pragma unroll
    for (int k = 0; k < 4; ++k) vb[k] = bn[(12 + k) * 64];    // n ks12..15
#pragma unroll
    for (int k = 0; k < 8; ++k) accNh = MFMA(ldA(h1c, col, 2 * (4 + k) + hv), va[k], accNh);
#pragma unroll
    for (int k = 0; k < 4; ++k) accNh = MFMA(ldA(h1c, col, 2 * (12 + k) + hv), vb[k], accNh);

    // combine h1 -> masters + h1n (swizzled bf16)
#pragma unroll
    for (int q = 0; q < 16; ++q) {
      float r = sigmoidf_(accR[q] + br1);
      float z = sigmoidf_(accZ[q] + bz1);
      float n = tanhf_(accNi[q] + bi1 + r * (accNh[q] + bh1));
      float h = (1.f - z) * n + z * h1r[q];
      h1r[q]  = h;
      int m = (q & 3) + 8 * (q >> 2) + 4 * hv;
      h1n[(m << 8) + (((jd >> 3) ^ m) << 3) + (jd & 7)] = bfb(h);
    }
    __syncthreads();  // bar1: h1n complete

    // ======== phase B: layer 2 (wih2·h1n folded with whh2·h2c) ========
    const bf16x8* cr = g_pk + F_WIH2 + w * 1024 + l;
    const bf16x8* cz = g_pk + F_WIH2 + (w + 8) * 1024 + l;
    const bf16x8* cn = g_pk + F_WIH2 + (w + 16) * 1024 + l;
    const bf16x8* dr = g_pk + F_WHH2 + w * 1024 + l;
    const bf16x8* dz = g_pk + F_WHH2 + (w + 8) * 1024 + l;
    const bf16x8* dn = g_pk + F_WHH2 + (w + 16) * 1024 + l;

#pragma unroll
    for (int k = 0; k < 8; ++k) va[k] = cr[k * 64];
#pragma unroll
    for (int k = 0; k < 8; ++k) vb[k] = cr[(8 + k) * 64];
    {
      f32x16 zz = z16();
      accR = zz; accZ = zz; accNi = zz; accNh = zz;
    }
#pragma unroll
    for (int k = 0; k < 8; ++k) accR = MFMA(ldA(h1n, col, 2 * k + hv), va[k], accR);
#pragma unroll
    for (int k = 0; k < 8; ++k) va[k] = cz[k * 64];
#pragma unroll
    for (int k = 0; k < 8; ++k) accR = MFMA(ldA(h1n, col, 2 * (8 + k) + hv), vb[k], accR);
#pragma unroll
    for (int k = 0; k < 8; ++k) vb[k] = cz[(8 + k) * 64];
#pragma unroll
    for (int k = 0; k < 8; ++k) accZ = MFMA(ldA(h1n, col, 2 * k + hv), va[k], accZ);
#pragma unroll
    for (int k = 0; k < 8; ++k) va[k] = cn[k * 64];
#pragma unroll
    for (int k = 0; k < 8; ++k) accZ = MFMA(ldA(h1n, col, 2 * (8 + k) + hv), vb[k], accZ);
#pragma unroll
    for (int k = 0; k < 8; ++k) vb[k] = cn[(8 + k) * 64];
#pragma unroll
    for (int k = 0; k < 8; ++k) accNi = MFMA(ldA(h1n, col, 2 * k + hv), va[k], accNi);
#pragma unroll
    for (int k = 0; k < 8; ++k) va[k] = dr[k * 64];
#pragma unroll
    for (int k = 0; k < 8; ++k) accNi = MFMA(ldA(h1n, col, 2 * (8 + k) + hv), vb[k], accNi);
#pragma unroll
    for (int k = 0; k < 8; ++k) vb[k] = dr[(8 + k) * 64];
    // whh2 chains fold into the same accs (A = h2c)
#pragma unroll
    for (int k = 0; k < 8; ++k) accR = MFMA(ldA(h2c, col, 2 * k + hv), va[k], accR);
#pragma unroll
    for (int k = 0; k < 8; ++k) va[k] = dz[k * 64];
#pragma unroll
    for (int k = 0; k < 8; ++k) accR = MFMA(ldA(h2c, col, 2 * (8 + k) + hv), vb[k], accR);
#pragma unroll
    for (int k = 0; k < 8; ++k) vb[k] = dz[(8 + k) * 64];
#pragma unroll
    for (int k = 0; k < 8; ++k) accZ = MFMA(ldA(h2c, col, 2 * k + hv), va[k], accZ);
#pragma unroll
    for (int k = 0; k < 8; ++k) va[k] = dn[k * 64];
#pragma unroll
    for (int k = 0; k < 8; ++k) accZ = MFMA(ldA(h2c, col, 2 * (8 + k) + hv), vb[k], accZ);
#pragma unroll
    for (int k = 0; k < 8; ++k) vb[k] = dn[(8 + k) * 64];
#pragma unroll
    for (int k = 0; k < 8; ++k) accNh = MFMA(ldA(h2c, col, 2 * k + hv), va[k], accNh);
#pragma unroll
    for (int k = 0; k < 8; ++k) accNh = MFMA(ldA(h2c, col, 2 * (8 + k) + hv), vb[k], accNh);

    // wave 2: prefetch head frags (land during combine + bar2)
    if (w == 2) {
      const bf16x8* ph = g_pk + F_LIN + l;
#pragma unroll
      for (int k = 0; k < 8; ++k) va[k] = ph[k * 64];
#pragma unroll
      for (int k = 0; k < 8; ++k) vb[k] = ph[(8 + k) * 64];
    }

    // combine h2 -> masters + h2n
#pragma unroll
    for (int q = 0; q < 16; ++q) {
      float r = sigmoidf_(accR[q] + br2);
      float z = sigmoidf_(accZ[q] + bz2);
      float n = tanhf_(accNi[q] + bi2 + r * (accNh[q] + bh2));
      float h = (1.f - z) * n + z * h2r[q];
      h2r[q]  = h;
      int m = (q & 3) + 8 * (q >> 2) + 4 * hv;
      h2n[(m << 8) + (((jd >> 3) ^ m) << 3) + (jd & 7)] = bfb(h);
    }
    __syncthreads();  // bar2: h2n complete

    // ======== head (wave 2) + next-step x (wave 3) ========
    if (w == 2) {
      f32x16 ao = z16();
#pragma unroll
      for (int k = 0; k < 8; ++k) ao = MFMA(ldA(h2n, col, 2 * k + hv), va[k], ao);
#pragma unroll
      for (int k = 0; k < 8; ++k) ao = MFMA(ldA(h2n, col, 2 * (8 + k) + hv), vb[k], ao);
      if (col < NOUT) {
#pragma unroll
        for (int q = 0; q < 16; ++q) {
          int m   = (q & 3) + 8 * (q >> 2) + 4 * hv;
          float v = ao[q] + lb;
          out[((size_t)(b0 + m) * T + t) * NOUT + col] = v;
          xs[(m << 4) + col] = bfb(v);
        }
      }
    } else if (w == 3 && t + 1 < T) {
      xs[(col << 4) + 5] = bfb(ux);
      xs[(col << 4) + 6] = bfb(uy);
      xs[(col << 4) + 7] = bfb(uz);
    }
    __syncthreads();  // bar3: xs ready for next step
  }
}

extern "C" void kernel_launch(void* const* d_in, const int* in_sizes, int n_in,
                              void* d_out, int out_size, void* d_ws, size_t ws_size,
                              hipStream_t stream) {
  (void)in_sizes; (void)n_in; (void)out_size; (void)d_ws; (void)ws_size;
  const int*   plen  = (const int*)d_in[0];
  const float* rnn   = (const float*)d_in[1];
  const float* out0  = (const float*)d_in[2];
  const float* h01   = (const float*)d_in[3];
  const float* h02   = (const float*)d_in[4];
  const float* wih1  = (const float*)d_in[5];
  const float* whh1  = (const float*)d_in[6];
  const float* bih1  = (const float*)d_in[7];
  const float* bhh1  = (const float*)d_in[8];
  const float* wih2  = (const float*)d_in[9];
  const float* whh2  = (const float*)d_in[10];
  const float* bih2  = (const float*)d_in[11];
  const float* bhh2  = (const float*)d_in[12];
  const float* lin_w = (const float*)d_in[13];
  const float* lin_b = (const float*)d_in[14];

  prepack_kernel<<<(F_TOTAL + 255) / 256, 256, 0, stream>>>(wih1, whh1, wih2, whh2, lin_w);
  gru_kernel<<<NBLK, 512, 0, stream>>>(plen, rnn, out0, h01, h02,
                                       bih1, bhh1, bih2, bhh2, lin_b,
                                       (float*)d_out);
}

// Round 8
// 15969.969 us; speedup vs baseline: 1.1926x; 1.1926x over previous
//
#include <hip/hip_runtime.h>

typedef __bf16 bf16;
typedef __bf16 bf16x8 __attribute__((ext_vector_type(8)));
typedef float  f32x16 __attribute__((ext_vector_type(16)));
typedef unsigned short u16;

#define MFMA(a,b,c) __builtin_amdgcn_mfma_f32_32x32x16_bf16((a),(b),(c),0,0,0)

#define BSZ  2048
#define H    256
#define NOUT 5
#define BM   32              // batch rows per block
#define NBLK (BSZ/BM)        // 64 blocks, zero inter-block communication

// packed weight fragments (16B each): big mats frag id = (tile*16+ks)*64+lane
// (VERIFIED layout, rounds 1-7)
#define F_WHH1 0
#define F_WIH2 24576
#define F_WHH2 49152
#define F_WIH1 73728
#define F_LIN  75264
#define F_TOTAL 76288

__device__ bf16x8 g_pk[F_TOTAL];

__global__ void prepack_kernel(const float* __restrict__ wih1,
                               const float* __restrict__ whh1,
                               const float* __restrict__ wih2,
                               const float* __restrict__ whh2,
                               const float* __restrict__ lin_w) {
  int fid = blockIdx.x * 256 + threadIdx.x;
  if (fid >= F_TOTAL) return;
  bf16x8 v;
  if (fid < F_WIH1) {
    const float* W = (fid < F_WIH2) ? whh1 : (fid < F_WHH2) ? wih2 : whh2;
    int r    = fid % 24576;
    int tile = r >> 10;
    int ks   = (r >> 6) & 15;
    int lane = r & 63;
    int n = tile * 32 + (lane & 31);
    int k = ks * 16 + (lane >> 5) * 8;
    const float* p = W + n * 256 + k;
#pragma unroll
    for (int i = 0; i < 8; ++i) v[i] = (bf16)p[i];
  } else if (fid < F_LIN) {
    int r    = fid - F_WIH1;
    int tile = r >> 6;
    int lane = r & 63;
    int n  = tile * 32 + (lane & 31);
    int k0 = (lane >> 5) * 8;
#pragma unroll
    for (int i = 0; i < 8; ++i) {
      int kk = k0 + i;
      v[i] = (kk < 8) ? (bf16)wih1[n * 8 + kk] : (bf16)0.f;
    }
  } else {
    int r    = fid - F_LIN;
    int ks   = r >> 6;
    int lane = r & 63;
    int n = lane & 31;
    int k = ks * 16 + (lane >> 5) * 8;
#pragma unroll
    for (int i = 0; i < 8; ++i)
      v[i] = (n < NOUT) ? (bf16)lin_w[n * 256 + k + i] : (bf16)0.f;
  }
  g_pk[fid] = v;
}

__device__ __forceinline__ float sigmoidf_(float x) { return 1.f / (1.f + __expf(-x)); }
__device__ __forceinline__ float tanhf_(float x) {
  float e = __expf(-2.f * x);
  return (1.f - e) / (1.f + e);
}
__device__ __forceinline__ u16 bfb(float x) { bf16 b = (bf16)x; return *(u16*)&b; }

// Zero-sync batch-split GRU (round-1 verified structure). Block b owns batch
// rows [32b,32b+32) for all T steps. 8 waves; wave w owns h-dims [32w,32w+32)
// via gate tiles {w, w+8, w+16}. Direct JIT B-frag loads from g_pk (no
// register staging arrays -> no spills). LDS = 153KB: forces 1 block/CU so
// each CU streams the weight set ONCE per step (round 1's 2 blocks/CU
// streamed it twice = its 17us/step floor); 88KB of whh1 is LDS-resident.
__global__ __launch_bounds__(512, 2) void gru_kernel(
    const int* __restrict__ plen_p,
    const float* __restrict__ rnn_in,
    const float* __restrict__ out0,
    const float* __restrict__ h01,
    const float* __restrict__ h02,
    const float* __restrict__ bih1, const float* __restrict__ bhh1,
    const float* __restrict__ bih2, const float* __restrict__ bhh2,
    const float* __restrict__ lin_b,
    float* __restrict__ out) {
  __shared__ u16 h1s[2][BM * 256];     // 16KB each, swizzled, double-buffered
  __shared__ u16 h2s[2][BM * 256];
  __shared__ u16 xs[BM * 16];          // [out(5), u(3), zeros(8)]
  __shared__ u16 ldsW[88 * 512];       // 88 LDS-resident frags (11/wave), 88KB

  const int T   = plen_p[0];
  const int tid = threadIdx.x;
  const int w   = tid >> 6;
  const int l   = tid & 63;
  const int col = l & 31;
  const int hv  = l >> 5;
  const int b0  = blockIdx.x * BM;
  const int jd  = w * 32 + col;        // this lane's h-dim / gate column

  // ---- per-lane biases ----
  float br1 = bih1[jd] + bhh1[jd];
  float bz1 = bih1[H + jd] + bhh1[H + jd];
  float bi1 = bih1[2 * H + jd];
  float bh1 = bhh1[2 * H + jd];
  float br2 = bih2[jd] + bhh2[jd];
  float bz2 = bih2[H + jd] + bhh2[H + jd];
  float bi2 = bih2[2 * H + jd];
  float bh2 = bhh2[2 * H + jd];
  float lb  = (col < NOUT) ? lin_b[col] : 0.f;

  // ---- LDS-resident frags (verified r7): slot w*11+j:
  //      j<7 -> whh1_r ks9+j ; j>=7 -> whh1_z ks(j-7) ----
#pragma unroll
  for (int j = 0; j < 11; ++j) {
    int src = (j < 7) ? (F_WHH1 + (w * 16 + 9 + j) * 64)
                      : (F_WHH1 + ((w + 8) * 16 + (j - 7)) * 64);
    bf16x8 f = g_pk[src + l];
    *(bf16x8*)&ldsW[(w * 11 + j) * 512 + l * 8] = f;
  }
#define LDSW(s) (*(const bf16x8*)&ldsW[(s) * 512 + l * 8])

  // ---- fp32 master h state in C/D layout: reg q -> row (q&3)+8*(q>>2)+4*hv
  float h1r[16], h2r[16];
#pragma unroll
  for (int q = 0; q < 16; ++q) {
    int m  = (q & 3) + 8 * (q >> 2) + 4 * hv;
    h1r[q] = h01[(size_t)(b0 + m) * H + jd];
    h2r[q] = h02[(size_t)(b0 + m) * H + jd];
  }

  // ---- LDS init: bf16 shadows (swizzled), x tile ----
  for (int idx = tid; idx < BM * 32; idx += 512) {
    int m = idx >> 5, u8 = idx & 31;
    const float* p1 = h01 + (size_t)(b0 + m) * H + u8 * 8;
    const float* p2 = h02 + (size_t)(b0 + m) * H + u8 * 8;
    bf16x8 v1, v2;
#pragma unroll
    for (int i = 0; i < 8; ++i) { v1[i] = (bf16)p1[i]; v2[i] = (bf16)p2[i]; }
    int off = (m << 8) + ((u8 ^ m) << 3);
    *(bf16x8*)&h1s[0][off] = v1;
    *(bf16x8*)&h2s[0][off] = v2;
  }
  if (tid < 256) { int m = tid >> 3, c = 8 + (tid & 7); xs[m * 16 + c] = 0; }
  if (tid < 160) { int m = tid / 5, o = tid % 5; xs[m * 16 + o] = bfb(out0[(size_t)(b0 + m) * NOUT + o]); }
  if (tid >= 256 && tid < 352) {
    int r = tid - 256; int m = r / 3, c = r % 3;
    xs[m * 16 + 5 + c] = bfb(rnn_in[(size_t)(b0 + m) * 4 + c]);
  }
  __syncthreads();

  const int am = col;  // A-fragment row for this lane
  int cur = 0;

  for (int t = 0; t < T; ++t) {
    const u16* h1c = h1s[cur];
    const u16* h2c = h2s[cur];
    u16* h1n = h1s[cur ^ 1];
    u16* h2n = h2s[cur ^ 1];

    // ================= layer 1 =================
    f32x16 ar, az, ahn, ain;
#pragma unroll
    for (int i = 0; i < 16; ++i) { ar[i] = 0.f; az[i] = 0.f; ahn[i] = 0.f; ain[i] = 0.f; }
    {
      const bf16x8* pr = g_pk + F_WHH1 + (w     ) * 1024 + l;
      const bf16x8* pz = g_pk + F_WHH1 + (w +  8) * 1024 + l;
      const bf16x8* pn = g_pk + F_WHH1 + (w + 16) * 1024 + l;
#pragma unroll
      for (int ks = 0; ks < 16; ++ks) {
        bf16x8 a = *(const bf16x8*)&h1c[am * 256 + (((2 * ks + hv) ^ am) << 3)];
        bf16x8 fr = (ks < 9) ? pr[ks * 64] : LDSW(w * 11 + (ks - 9));
        bf16x8 fz = (ks < 4) ? LDSW(w * 11 + 7 + ks) : pz[ks * 64];
        ar  = MFMA(a, fr, ar);
        az  = MFMA(a, fz, az);
        ahn = MFMA(a, pn[ks * 64], ahn);
      }
      bf16x8 ax = *(const bf16x8*)&xs[am * 16 + hv * 8];
      ar  = MFMA(ax, g_pk[F_WIH1 + (w     ) * 64 + l], ar);
      az  = MFMA(ax, g_pk[F_WIH1 + (w +  8) * 64 + l], az);
      ain = MFMA(ax, g_pk[F_WIH1 + (w + 16) * 64 + l], ain);
    }
#pragma unroll
    for (int q = 0; q < 16; ++q) {
      float r = sigmoidf_(ar[q] + br1);
      float z = sigmoidf_(az[q] + bz1);
      float n = tanhf_(ain[q] + bi1 + r * (ahn[q] + bh1));
      float h = (1.f - z) * n + z * h1r[q];
      h1r[q]  = h;
      int m = (q & 3) + 8 * (q >> 2) + 4 * hv;
      h1n[m * 256 + (((jd >> 3) ^ m) << 3) + (jd & 7)] = bfb(h);
    }
    __syncthreads();

    // ================= layer 2 =================
#pragma unroll
    for (int i = 0; i < 16; ++i) { ar[i] = 0.f; az[i] = 0.f; ahn[i] = 0.f; ain[i] = 0.f; }
    {
      const bf16x8* pr = g_pk + F_WIH2 + (w     ) * 1024 + l;
      const bf16x8* pz = g_pk + F_WIH2 + (w +  8) * 1024 + l;
      const bf16x8* pn = g_pk + F_WIH2 + (w + 16) * 1024 + l;
#pragma unroll
      for (int ks = 0; ks < 16; ++ks) {
        bf16x8 a = *(const bf16x8*)&h1n[am * 256 + (((2 * ks + hv) ^ am) << 3)];
        ar  = MFMA(a, pr[ks * 64], ar);
        az  = MFMA(a, pz[ks * 64], az);
        ain = MFMA(a, pn[ks * 64], ain);
      }
    }
    {
      const bf16x8* pr = g_pk + F_WHH2 + (w     ) * 1024 + l;
      const bf16x8* pz = g_pk + F_WHH2 + (w +  8) * 1024 + l;
      const bf16x8* pn = g_pk + F_WHH2 + (w + 16) * 1024 + l;
#pragma unroll
      for (int ks = 0; ks < 16; ++ks) {
        bf16x8 a = *(const bf16x8*)&h2c[am * 256 + (((2 * ks + hv) ^ am) << 3)];
        ar  = MFMA(a, pr[ks * 64], ar);
        az  = MFMA(a, pz[ks * 64], az);
        ahn = MFMA(a, pn[ks * 64], ahn);
      }
    }
#pragma unroll
    for (int q = 0; q < 16; ++q) {
      float r = sigmoidf_(ar[q] + br2);
      float z = sigmoidf_(az[q] + bz2);
      float n = tanhf_(ain[q] + bi2 + r * (ahn[q] + bh2));
      float h = (1.f - z) * n + z * h2r[q];
      h2r[q]  = h;
      int m = (q & 3) + 8 * (q >> 2) + 4 * hv;
      h2n[m * 256 + (((jd >> 3) ^ m) << 3) + (jd & 7)] = bfb(h);
    }
    __syncthreads();

    // ================= output head + next-step x =================
    if (w == 0) {
      f32x16 ao;
#pragma unroll
      for (int i = 0; i < 16; ++i) ao[i] = 0.f;
      const bf16x8* po = g_pk + F_LIN + l;
#pragma unroll
      for (int ks = 0; ks < 16; ++ks) {
        bf16x8 a = *(const bf16x8*)&h2n[am * 256 + (((2 * ks + hv) ^ am) << 3)];
        ao = MFMA(a, po[ks * 64], ao);
      }
      if (col < NOUT) {
#pragma unroll
        for (int q = 0; q < 16; ++q) {
          int m   = (q & 3) + 8 * (q >> 2) + 4 * hv;
          float v = ao[q] + lb;
          out[((size_t)(b0 + m) * T + t) * NOUT + col] = v;
          xs[m * 16 + col] = bfb(v);
        }
      }
    }
    if (w == 1 && t + 1 < T) {
      for (int j = l; j < 96; j += 64) {
        int m = j / 3, c = j % 3;
        xs[m * 16 + 5 + c] = bfb(rnn_in[((size_t)(t + 1) * BSZ + b0 + m) * 4 + c]);
      }
    }
    __syncthreads();
    cur ^= 1;
  }
}

extern "C" void kernel_launch(void* const* d_in, const int* in_sizes, int n_in,
                              void* d_out, int out_size, void* d_ws, size_t ws_size,
                              hipStream_t stream) {
  (void)in_sizes; (void)n_in; (void)out_size; (void)d_ws; (void)ws_size;
  const int*   plen  = (const int*)d_in[0];
  const float* rnn   = (const float*)d_in[1];
  const float* out0  = (const float*)d_in[2];
  const float* h01   = (const float*)d_in[3];
  const float* h02   = (const float*)d_in[4];
  const float* wih1  = (const float*)d_in[5];
  const float* whh1  = (const float*)d_in[6];
  const float* bih1  = (const float*)d_in[7];
  const float* bhh1  = (const float*)d_in[8];
  const float* wih2  = (const float*)d_in[9];
  const float* whh2  = (const float*)d_in[10];
  const float* bih2  = (const float*)d_in[11];
  const float* bhh2  = (const float*)d_in[12];
  const float* lin_w = (const float*)d_in[13];
  const float* lin_b = (const float*)d_in[14];

  prepack_kernel<<<(F_TOTAL + 255) / 256, 256, 0, stream>>>(wih1, whh1, wih2, whh2, lin_w);
  gru_kernel<<<NBLK, 512, 0, stream>>>(plen, rnn, out0, h01, h02,
                                       bih1, bhh1, bih2, bhh2, lin_b,
                                       (float*)d_out);
}

// Round 9
// 6753.767 us; speedup vs baseline: 2.8201x; 2.3646x over previous
//
#include <hip/hip_runtime.h>

typedef __bf16 bf16;
typedef __bf16 bf16x8 __attribute__((ext_vector_type(8)));
typedef float  f32x16 __attribute__((ext_vector_type(16)));
typedef unsigned short u16;

#define MFMA(a,b,c) __builtin_amdgcn_mfma_f32_32x32x16_bf16((a),(b),(c),0,0,0)

#define BSZ  2048
#define H    256
#define NOUT 5
#define BM   32              // batch rows per block
#define NBLK (BSZ/BM)        // 64 blocks, zero inter-block communication

// packed weight fragments (16B each): big mats frag id = (tile*16+ks)*64+lane
// (VERIFIED layout, rounds 1-8)
#define F_WHH1 0
#define F_WIH2 24576
#define F_WHH2 49152
#define F_WIH1 73728
#define F_LIN  75264
#define F_TOTAL 76288

__device__ bf16x8 g_pk[F_TOTAL];

__global__ void prepack_kernel(const float* __restrict__ wih1,
                               const float* __restrict__ whh1,
                               const float* __restrict__ wih2,
                               const float* __restrict__ whh2,
                               const float* __restrict__ lin_w) {
  int fid = blockIdx.x * 256 + threadIdx.x;
  if (fid >= F_TOTAL) return;
  bf16x8 v;
  if (fid < F_WIH1) {
    const float* W = (fid < F_WIH2) ? whh1 : (fid < F_WHH2) ? wih2 : whh2;
    int r    = fid % 24576;
    int tile = r >> 10;
    int ks   = (r >> 6) & 15;
    int lane = r & 63;
    int n = tile * 32 + (lane & 31);
    int k = ks * 16 + (lane >> 5) * 8;
    const float* p = W + n * 256 + k;
#pragma unroll
    for (int i = 0; i < 8; ++i) v[i] = (bf16)p[i];
  } else if (fid < F_LIN) {
    int r    = fid - F_WIH1;
    int tile = r >> 6;
    int lane = r & 63;
    int n  = tile * 32 + (lane & 31);
    int k0 = (lane >> 5) * 8;
#pragma unroll
    for (int i = 0; i < 8; ++i) {
      int kk = k0 + i;
      v[i] = (kk < 8) ? (bf16)wih1[n * 8 + kk] : (bf16)0.f;
    }
  } else {
    int r    = fid - F_LIN;
    int ks   = r >> 6;
    int lane = r & 63;
    int n = lane & 31;
    int k = ks * 16 + (lane >> 5) * 8;
#pragma unroll
    for (int i = 0; i < 8; ++i)
      v[i] = (n < NOUT) ? (bf16)lin_w[n * 256 + k + i] : (bf16)0.f;
  }
  g_pk[fid] = v;
}

__device__ __forceinline__ float sigmoidf_(float x) { return 1.f / (1.f + __expf(-x)); }
__device__ __forceinline__ float tanhf_(float x) {
  float e = __expf(-2.f * x);
  return (1.f - e) / (1.f + e);
}
__device__ __forceinline__ u16 bfb(float x) { bf16 b = (bf16)x; return *(u16*)&b; }

// Zero-sync batch-split GRU (round-1 verified structure; ks loops kept ROLLED
// — full unroll made the t-loop body overflow the I-cache: r7/r8's 5.7GB
// FETCH / 1.5% MfmaUtil regression). Block b owns batch rows [32b,32b+32).
// 8 waves; wave w owns h-dims [32w,32w+32) via gate tiles {w, w+8, w+16}.
// 88KB of whh1 is LDS-resident (trims L2 weight stream 1.21->1.04 MB/step).
__global__ __launch_bounds__(512, 2) void gru_kernel(
    const int* __restrict__ plen_p,
    const float* __restrict__ rnn_in,
    const float* __restrict__ out0,
    const float* __restrict__ h01,
    const float* __restrict__ h02,
    const float* __restrict__ bih1, const float* __restrict__ bhh1,
    const float* __restrict__ bih2, const float* __restrict__ bhh2,
    const float* __restrict__ lin_b,
    float* __restrict__ out) {
  __shared__ u16 h1s[2][BM * 256];     // 16KB each, swizzled, double-buffered
  __shared__ u16 h2s[2][BM * 256];
  __shared__ u16 xs[BM * 16];          // [out(5), u(3), zeros(8)]
  __shared__ u16 ldsW[88 * 512];       // 88 LDS-resident frags (11/wave), 88KB

  const int T   = plen_p[0];
  const int tid = threadIdx.x;
  const int w   = tid >> 6;
  const int l   = tid & 63;
  const int col = l & 31;
  const int hv  = l >> 5;
  const int b0  = blockIdx.x * BM;
  const int jd  = w * 32 + col;        // this lane's h-dim / gate column

  // ---- per-lane biases ----
  float br1 = bih1[jd] + bhh1[jd];
  float bz1 = bih1[H + jd] + bhh1[H + jd];
  float bi1 = bih1[2 * H + jd];
  float bh1 = bhh1[2 * H + jd];
  float br2 = bih2[jd] + bhh2[jd];
  float bz2 = bih2[H + jd] + bhh2[H + jd];
  float bi2 = bih2[2 * H + jd];
  float bh2 = bhh2[2 * H + jd];
  float lb  = (col < NOUT) ? lin_b[col] : 0.f;

  // ---- LDS-resident frags (verified r7/r8): slot w*11+j:
  //      j<7 -> whh1_r ks9+j ; j>=7 -> whh1_z ks(j-7) ----
#pragma unroll
  for (int j = 0; j < 11; ++j) {
    int src = (j < 7) ? (F_WHH1 + (w * 16 + 9 + j) * 64)
                      : (F_WHH1 + ((w + 8) * 16 + (j - 7)) * 64);
    bf16x8 f = g_pk[src + l];
    *(bf16x8*)&ldsW[(w * 11 + j) * 512 + l * 8] = f;
  }
#define LDSW(s) (*(const bf16x8*)&ldsW[(s) * 512 + l * 8])

  // ---- fp32 master h state in C/D layout: reg q -> row (q&3)+8*(q>>2)+4*hv
  float h1r[16], h2r[16];
#pragma unroll
  for (int q = 0; q < 16; ++q) {
    int m  = (q & 3) + 8 * (q >> 2) + 4 * hv;
    h1r[q] = h01[(size_t)(b0 + m) * H + jd];
    h2r[q] = h02[(size_t)(b0 + m) * H + jd];
  }

  // ---- LDS init: bf16 shadows (swizzled), x tile ----
  for (int idx = tid; idx < BM * 32; idx += 512) {
    int m = idx >> 5, u8 = idx & 31;
    const float* p1 = h01 + (size_t)(b0 + m) * H + u8 * 8;
    const float* p2 = h02 + (size_t)(b0 + m) * H + u8 * 8;
    bf16x8 v1, v2;
#pragma unroll
    for (int i = 0; i < 8; ++i) { v1[i] = (bf16)p1[i]; v2[i] = (bf16)p2[i]; }
    int off = (m << 8) + ((u8 ^ m) << 3);
    *(bf16x8*)&h1s[0][off] = v1;
    *(bf16x8*)&h2s[0][off] = v2;
  }
  if (tid < 256) { int m = tid >> 3, c = 8 + (tid & 7); xs[m * 16 + c] = 0; }
  if (tid < 160) { int m = tid / 5, o = tid % 5; xs[m * 16 + o] = bfb(out0[(size_t)(b0 + m) * NOUT + o]); }
  if (tid >= 256 && tid < 352) {
    int r = tid - 256; int m = r / 3, c = r % 3;
    xs[m * 16 + 5 + c] = bfb(rnn_in[(size_t)(b0 + m) * 4 + c]);
  }
  __syncthreads();

  const int am = col;  // A-fragment row for this lane
  int cur = 0;

  for (int t = 0; t < T; ++t) {
    const u16* h1c = h1s[cur];
    const u16* h2c = h2s[cur];
    u16* h1n = h1s[cur ^ 1];
    u16* h2n = h2s[cur ^ 1];

    // ================= layer 1 =================
    f32x16 ar, az, ahn, ain;
#pragma unroll
    for (int i = 0; i < 16; ++i) { ar[i] = 0.f; az[i] = 0.f; ahn[i] = 0.f; ain[i] = 0.f; }
    {
      const bf16x8* pr = g_pk + F_WHH1 + (w     ) * 1024 + l;
      const bf16x8* pz = g_pk + F_WHH1 + (w +  8) * 1024 + l;
      const bf16x8* pn = g_pk + F_WHH1 + (w + 16) * 1024 + l;
      // ks 0..3: z-gate frag from LDS
#pragma unroll 2
      for (int ks = 0; ks < 4; ++ks) {
        bf16x8 a = *(const bf16x8*)&h1c[am * 256 + (((2 * ks + hv) ^ am) << 3)];
        ar  = MFMA(a, pr[ks * 64], ar);
        az  = MFMA(a, LDSW(w * 11 + 7 + ks), az);
        ahn = MFMA(a, pn[ks * 64], ahn);
      }
      // ks 4..8: all from L2
#pragma unroll 2
      for (int ks = 4; ks < 9; ++ks) {
        bf16x8 a = *(const bf16x8*)&h1c[am * 256 + (((2 * ks + hv) ^ am) << 3)];
        ar  = MFMA(a, pr[ks * 64], ar);
        az  = MFMA(a, pz[ks * 64], az);
        ahn = MFMA(a, pn[ks * 64], ahn);
      }
      // ks 9..15: r-gate frag from LDS
#pragma unroll 2
      for (int ks = 9; ks < 16; ++ks) {
        bf16x8 a = *(const bf16x8*)&h1c[am * 256 + (((2 * ks + hv) ^ am) << 3)];
        ar  = MFMA(a, LDSW(w * 11 + (ks - 9)), ar);
        az  = MFMA(a, pz[ks * 64], az);
        ahn = MFMA(a, pn[ks * 64], ahn);
      }
      bf16x8 ax = *(const bf16x8*)&xs[am * 16 + hv * 8];
      ar  = MFMA(ax, g_pk[F_WIH1 + (w     ) * 64 + l], ar);
      az  = MFMA(ax, g_pk[F_WIH1 + (w +  8) * 64 + l], az);
      ain = MFMA(ax, g_pk[F_WIH1 + (w + 16) * 64 + l], ain);
    }
#pragma unroll
    for (int q = 0; q < 16; ++q) {
      float r = sigmoidf_(ar[q] + br1);
      float z = sigmoidf_(az[q] + bz1);
      float n = tanhf_(ain[q] + bi1 + r * (ahn[q] + bh1));
      float h = (1.f - z) * n + z * h1r[q];
      h1r[q]  = h;
      int m = (q & 3) + 8 * (q >> 2) + 4 * hv;
      h1n[m * 256 + (((jd >> 3) ^ m) << 3) + (jd & 7)] = bfb(h);
    }
    __syncthreads();

    // ================= layer 2 =================
#pragma unroll
    for (int i = 0; i < 16; ++i) { ar[i] = 0.f; az[i] = 0.f; ahn[i] = 0.f; ain[i] = 0.f; }
    {
      const bf16x8* pr = g_pk + F_WIH2 + (w     ) * 1024 + l;
      const bf16x8* pz = g_pk + F_WIH2 + (w +  8) * 1024 + l;
      const bf16x8* pn = g_pk + F_WIH2 + (w + 16) * 1024 + l;
#pragma unroll 4
      for (int ks = 0; ks < 16; ++ks) {
        bf16x8 a = *(const bf16x8*)&h1n[am * 256 + (((2 * ks + hv) ^ am) << 3)];
        ar  = MFMA(a, pr[ks * 64], ar);
        az  = MFMA(a, pz[ks * 64], az);
        ain = MFMA(a, pn[ks * 64], ain);
      }
    }
    {
      const bf16x8* pr = g_pk + F_WHH2 + (w     ) * 1024 + l;
      const bf16x8* pz = g_pk + F_WHH2 + (w +  8) * 1024 + l;
      const bf16x8* pn = g_pk + F_WHH2 + (w + 16) * 1024 + l;
#pragma unroll 4
      for (int ks = 0; ks < 16; ++ks) {
        bf16x8 a = *(const bf16x8*)&h2c[am * 256 + (((2 * ks + hv) ^ am) << 3)];
        ar  = MFMA(a, pr[ks * 64], ar);
        az  = MFMA(a, pz[ks * 64], az);
        ahn = MFMA(a, pn[ks * 64], ahn);
      }
    }
#pragma unroll
    for (int q = 0; q < 16; ++q) {
      float r = sigmoidf_(ar[q] + br2);
      float z = sigmoidf_(az[q] + bz2);
      float n = tanhf_(ain[q] + bi2 + r * (ahn[q] + bh2));
      float h = (1.f - z) * n + z * h2r[q];
      h2r[q]  = h;
      int m = (q & 3) + 8 * (q >> 2) + 4 * hv;
      h2n[m * 256 + (((jd >> 3) ^ m) << 3) + (jd & 7)] = bfb(h);
    }
    __syncthreads();

    // ================= output head + next-step x =================
    if (w == 0) {
      f32x16 ao;
#pragma unroll
      for (int i = 0; i < 16; ++i) ao[i] = 0.f;
      const bf16x8* po = g_pk + F_LIN + l;
#pragma unroll 4
      for (int ks = 0; ks < 16; ++ks) {
        bf16x8 a = *(const bf16x8*)&h2n[am * 256 + (((2 * ks + hv) ^ am) << 3)];
        ao = MFMA(a, po[ks * 64], ao);
      }
      if (col < NOUT) {
#pragma unroll
        for (int q = 0; q < 16; ++q) {
          int m   = (q & 3) + 8 * (q >> 2) + 4 * hv;
          float v = ao[q] + lb;
          out[((size_t)(b0 + m) * T + t) * NOUT + col] = v;
          xs[m * 16 + col] = bfb(v);
        }
      }
    }
    if (w == 1 && t + 1 < T) {
      for (int j = l; j < 96; j += 64) {
        int m = j / 3, c = j % 3;
        xs[m * 16 + 5 + c] = bfb(rnn_in[((size_t)(t + 1) * BSZ + b0 + m) * 4 + c]);
      }
    }
    __syncthreads();
    cur ^= 1;
  }
}

extern "C" void kernel_launch(void* const* d_in, const int* in_sizes, int n_in,
                              void* d_out, int out_size, void* d_ws, size_t ws_size,
                              hipStream_t stream) {
  (void)in_sizes; (void)n_in; (void)out_size; (void)d_ws; (void)ws_size;
  const int*   plen  = (const int*)d_in[0];
  const float* rnn   = (const float*)d_in[1];
  const float* out0  = (const float*)d_in[2];
  const float* h01   = (const float*)d_in[3];
  const float* h02   = (const float*)d_in[4];
  const float* wih1  = (const float*)d_in[5];
  const float* whh1  = (const float*)d_in[6];
  const float* bih1  = (const float*)d_in[7];
  const float* bhh1  = (const float*)d_in[8];
  const float* wih2  = (const float*)d_in[9];
  const float* whh2  = (const float*)d_in[10];
  const float* bih2  = (const float*)d_in[11];
  const float* bhh2  = (const float*)d_in[12];
  const float* lin_w = (const float*)d_in[13];
  const float* lin_b = (const float*)d_in[14];

  prepack_kernel<<<(F_TOTAL + 255) / 256, 256, 0, stream>>>(wih1, whh1, wih2, whh2, lin_w);
  gru_kernel<<<NBLK, 512, 0, stream>>>(plen, rnn, out0, h01, h02,
                                       bih1, bhh1, bih2, bhh2, lin_b,
                                       (float*)d_out);
}